// Round 2
// baseline (112.963 us; speedup 1.0000x reference)
//
#include <hip/hip_runtime.h>

// RBFNN fused, round 9: M=64 tile @ 512 threads + lgkm-only chunk barrier.
// out[B,K] = exp(-gamma * dist(x, centers)) @ W^T + b
// B=16384, F=512, C=1024, K=100.
//
// R8 post-mortem: MX fp8 gave -1.9us (predicted -4.7 if MFMA-exposed) ->
// GEMM1 now rides the cb L2 stream (512 blocks x 512KB = 256MB = 7.4us @
// 34.5TB/s). Fixes this round:
//  1. M=64 rows/block, 512 thr (8 waves = 2x4 over rows x centers). Halves
//     block count -> cb traffic 256->128MB, wb same; per-thread regs are
//     IDENTICAL to R8 (acc1[2][4], bp ring-3 96v, wp 64v).
//  2. LDS ~102KB (a_lds 33.8K + phi dbuf 67.6K) -> 1 block/CU, still
//     2 waves/SIMD. To compensate for lost cross-block overlap the chunk
//     barrier is now s_waitcnt lgkmcnt(0) + raw s_barrier: phi publication
//     only needs lgkm; bp/wp preloads stay in flight across the barrier
//     (compiler inserts counted vmcnt at first use).
//  Race audit unchanged from R6: epilogue(c) writes phi[c&1]; GEMM2(c-1)
//  reads phi[(c-1)&1] (other buffer); no wave reaches epilogue(c+1)
//  without passing barrier(c).

#define NB 16384
#define NF 512
#define NC 1024
#define NK 100

#define A_PITCH 528   // bytes/row (512 fp8 + 16 pad)
#define P_PITCH 264   // shorts/row (256 bf16 + 8 pad)

#define CB_BYTES (NC * NF)      // 512KB fp8 centers, MX-frag-ordered
#define WB_BYTES (256 * 1024)   // 256KB bf16 W (100->128 kouts), frag-ordered
#define WS_NEED (CB_BYTES + NC * 4 + WB_BYTES)

typedef __attribute__((ext_vector_type(8))) short short8;
typedef __attribute__((ext_vector_type(4))) short short4v;
typedef __attribute__((ext_vector_type(4))) float f4;
typedef __attribute__((ext_vector_type(4))) unsigned int uint4v;
typedef __attribute__((ext_vector_type(8))) int int8v;
typedef unsigned short ushort;
typedef unsigned int uint;

__device__ __forceinline__ short bf16t(float f) {
  return (short)(__float_as_uint(f) >> 16);
}

__device__ __forceinline__ uint pk4_fp8(float a, float b, float c, float d) {
  uint r = __builtin_amdgcn_cvt_pk_fp8_f32(a, b, 0, false);
  return __builtin_amdgcn_cvt_pk_fp8_f32(c, d, r, true);
}

// lgkm-only barrier: publishes LDS writes but leaves global preloads in
// flight (their consumers get compiler-counted vmcnt waits).
__device__ __forceinline__ void soft_barrier() {
  asm volatile("s_waitcnt lgkmcnt(0)" ::: "memory");
  __builtin_amdgcn_s_barrier();
  asm volatile("" ::: "memory");
}

// ---------------- merged prepass (unchanged from R8) ----------------
// blocks 0..31: centers [1024,512] fp32 -> cb fp8 MX-fragment-ordered + csq.
//   cb addr ((c*4+ks)*16 + tg)*2048 + lane*32, lane = lg*16+lm:
//   32B = fp8 ctr[c*256 + tg*16 + lm][ks*128 + lg*32 .. +31]  (k-linear).
// blocks 32..33: W [100,1024] fp32 -> wb bf16 fragment-ordered, 128 kouts.
__global__ __launch_bounds__(256) void prep_all(
    const float* __restrict__ ctr, const float* __restrict__ W,
    char* __restrict__ cb, float* __restrict__ csq, char* __restrict__ wb) {
  if (blockIdx.x < 32) {
    const int t = blockIdx.x * 256 + threadIdx.x;  // 0..8191
    const int cg = t >> 3;                          // center row 0..1023
    const int kb = t & 7;                           // 64-k block
    const f4* src = (const f4*)(ctr + (size_t)cg * NF + kb * 64);
    float f[64];
    float ss = 0.f;
#pragma unroll
    for (int i = 0; i < 16; ++i) {
      f4 v = src[i];
      f[4 * i] = v.x; f[4 * i + 1] = v.y; f[4 * i + 2] = v.z; f[4 * i + 3] = v.w;
      ss += v.x * v.x + v.y * v.y + v.z * v.z + v.w * v.w;
    }
    uint w[16];
#pragma unroll
    for (int m = 0; m < 16; ++m)
      w[m] = pk4_fp8(f[4 * m], f[4 * m + 1], f[4 * m + 2], f[4 * m + 3]);
    const int c = cg >> 8, tg = (cg >> 4) & 15, lm = cg & 15;
    const int ks = kb >> 1, half = kb & 1;  // lg slots: half*2, half*2+1
    char* base = cb + (size_t)(((c * 4 + ks) * 16 + tg) << 11) + lm * 32 +
                 half * 1024;
    uint4v u0 = {w[0], w[1], w[2], w[3]};
    uint4v u1 = {w[4], w[5], w[6], w[7]};
    uint4v u2 = {w[8], w[9], w[10], w[11]};
    uint4v u3 = {w[12], w[13], w[14], w[15]};
    *(uint4v*)(base) = u0;          // lg slot half*2,   k-local  0..31
    *(uint4v*)(base + 16) = u1;
    *(uint4v*)(base + 512) = u2;    // lg slot half*2+1, k-local 32..63
    *(uint4v*)(base + 528) = u3;
    ss += __shfl_down(ss, 4, 64);
    ss += __shfl_down(ss, 2, 64);
    ss += __shfl_down(ss, 1, 64);
    if (kb == 0) csq[cg] = ss;
  } else {
    const int t = (blockIdx.x - 32) * 256 + threadIdx.x;  // 0..511
    const int kout = t >> 2, c = t & 3;
    const int kf = kout >> 4, lm = kout & 15;
#pragma unroll
    for (int ks = 0; ks < 8; ++ks) {
#pragma unroll
      for (int lg = 0; lg < 4; ++lg) {
        short4v h0 = {0, 0, 0, 0}, h1 = {0, 0, 0, 0};
        if (kout < NK) {
          const float* src = W + (size_t)kout * NC + c * 256 + ks * 32 + lg * 8;
          f4 v0 = ((const f4*)src)[0], v1 = ((const f4*)src)[1];
          h0.x = bf16t(v0.x); h0.y = bf16t(v0.y); h0.z = bf16t(v0.z); h0.w = bf16t(v0.w);
          h1.x = bf16t(v1.x); h1.y = bf16t(v1.y); h1.z = bf16t(v1.z); h1.w = bf16t(v1.w);
        }
        char* dst = wb + (size_t)((c * 8 + ks) * 8 + kf) * 1024 +
                    (lg * 16 + lm) * 16;
        *(short4v*)dst = h0;
        *(short4v*)(dst + 8) = h1;
      }
    }
  }
}

// ---------------- main kernel: M=64, 512 threads, 8 waves (2 rowg x 4 colg) ----------------

__global__ __launch_bounds__(512, 2)
void rbf_main(const float* __restrict__ x, const char* __restrict__ cb2,
              const float* __restrict__ csqp, const char* __restrict__ wb2,
              const float* __restrict__ bvec, const float* __restrict__ gamma_p,
              float* __restrict__ out) {
  __shared__ alignas(16) char a_lds[64 * A_PITCH];        // 33792 B, x fp8
  __shared__ alignas(16) short phi_lds[2][64 * P_PITCH];  // 67584 B, phi dbuf
  __shared__ float xsq[64];

  const int tid = threadIdx.x;
  const int lane = tid & 63;
  const int wv = tid >> 6;   // 0..7
  const int wr = wv >> 2;    // row group 0..1 (32 rows each)
  const int wc = wv & 3;     // center/kout column group 0..3
  const int lm = lane & 15;
  const int lg = lane >> 4;
  const int m0 = blockIdx.x * 64;
  const float gma = gamma_p[0];
  const int laneoff32 = lane << 5;  // 32B B-frags (MX K=128)
  const int laneoff16 = lane << 4;  // 16B W-frags

  // ---- prologue: stage x tile (fp32->fp8, k-LINEAR) + xsq ----
  {
    const int row = tid >> 3;   // 0..63
    const int seg = tid & 7;    // k block of 64
    const f4* xr = (const f4*)(x + (size_t)(m0 + row) * NF + seg * 64);
    float f[64];
    float ss = 0.f;
#pragma unroll
    for (int i = 0; i < 16; ++i) {
      f4 v = xr[i];
      f[4 * i] = v.x; f[4 * i + 1] = v.y; f[4 * i + 2] = v.z; f[4 * i + 3] = v.w;
      ss += v.x * v.x + v.y * v.y + v.z * v.z + v.w * v.w;
    }
    uint w[16];
#pragma unroll
    for (int m = 0; m < 16; ++m)
      w[m] = pk4_fp8(f[4 * m], f[4 * m + 1], f[4 * m + 2], f[4 * m + 3]);
    char* ar = a_lds + row * A_PITCH + seg * 64;
#pragma unroll
    for (int l2 = 0; l2 < 4; ++l2) {
      uint4v u = {w[4 * l2], w[4 * l2 + 1], w[4 * l2 + 2], w[4 * l2 + 3]};
      *(uint4v*)(ar + l2 * 16) = u;  // byte offset == k (linear)
    }
    ((float*)phi_lds[0])[tid] = ss;  // scratch partials (consumed pre-E0)
  }

  // B frag ring buffer (32B/frag); preload chunk-0 stages ks=0,1
  int8v bp[3][4];
#pragma unroll
  for (int t = 0; t < 4; ++t) {
    bp[0][t] = *(const int8v*)(cb2 + ((wc + 4 * t) << 11) + laneoff32);
    bp[1][t] = *(const int8v*)(cb2 + ((16 + wc + 4 * t) << 11) + laneoff32);
  }

  __syncthreads();  // publishes a_lds + partials
  if (tid < 64) {
    const float* pp = (const float*)phi_lds[0] + 8 * tid;
    xsq[tid] = pp[0] + pp[1] + pp[2] + pp[3] + pp[4] + pp[5] + pp[6] + pp[7];
  }
  __syncthreads();  // publishes xsq

  const f4 fzero = {0.f, 0.f, 0.f, 0.f};
  f4 acc2[2][2];
#pragma unroll
  for (int i = 0; i < 2; ++i)
#pragma unroll
    for (int n = 0; n < 2; ++n) acc2[i][n] = fzero;

  for (int c = 0; c < 4; ++c) {
    float csr[4];
#pragma unroll
    for (int t = 0; t < 4; ++t)
      csr[t] = csqp[c * 256 + 16 * (wc + 4 * t) + lm];

    f4 acc1[2][4];
#pragma unroll
    for (int i = 0; i < 2; ++i)
#pragma unroll
      for (int t = 0; t < 4; ++t) acc1[i][t] = fzero;

    // ---- GEMM1: 4 k=128 MX stages, no barriers, B ring-3 (distance 2) ----
    const char* bb = cb2 + (size_t)c * 131072;
#pragma unroll
    for (int ks = 0; ks < 4; ++ks) {
      if (ks < 2) {
#pragma unroll
        for (int t = 0; t < 4; ++t)
          bp[(ks + 2) % 3][t] = *(const int8v*)(
              bb + ((((ks + 2) * 16) + wc + 4 * t) << 11) + laneoff32);
      }
      int8v a2[2];
#pragma unroll
      for (int i = 0; i < 2; ++i)
        a2[i] = *(const int8v*)(a_lds + (32 * wr + 16 * i + lm) * A_PITCH +
                                ks * 128 + lg * 32);
      const int cur = ks % 3;
#pragma unroll
      for (int i = 0; i < 2; ++i)
#pragma unroll
        for (int t = 0; t < 4; ++t)
          acc1[i][t] = __builtin_amdgcn_mfma_scale_f32_16x16x128_f8f6f4(
              a2[i], bp[cur][t], acc1[i][t],
              0 /*fmt A=e4m3*/, 0 /*fmt B=e4m3*/,
              0, 0x7F7F7F7F,    /* scale A = 1.0 */
              0, 0x7F7F7F7F);   /* scale B = 1.0 */
    }

    // ---- preloads (in flight across epilogue + barrier) ----
    const char* wwb = wb2 + (size_t)c * 65536;
    short8 wp[8][2];
#pragma unroll
    for (int ks = 0; ks < 8; ++ks)
#pragma unroll
      for (int n = 0; n < 2; ++n)
        wp[ks][n] = *(const short8*)(wwb + ((ks * 8 + 2 * wc + n) << 10) +
                                     laneoff16);
    if (c < 3) {
      const char* bbn = cb2 + (size_t)(c + 1) * 131072;
#pragma unroll
      for (int t = 0; t < 4; ++t) {
        bp[0][t] = *(const int8v*)(bbn + ((wc + 4 * t) << 11) + laneoff32);
        bp[1][t] = *(const int8v*)(bbn + ((16 + wc + 4 * t) << 11) + laneoff32);
      }
    }

    // ---- epilogue: phi = exp(-gamma*dist) -> phi_lds[c&1] (A layout) ----
    short* phb = phi_lds[c & 1];
#pragma unroll
    for (int t = 0; t < 4; ++t) {
      const float cs = csr[t];
      const int colh = 16 * (wc + 4 * t) + lm;
#pragma unroll
      for (int i = 0; i < 2; ++i) {
#pragma unroll
        for (int r = 0; r < 4; ++r) {
          const int rowL = 32 * wr + 16 * i + 4 * lg + r;
          float d2 = xsq[rowL] + cs - 2.0f * acc1[i][t][r];
          d2 = fmaxf(d2, 0.f);
          const float ph = __expf(-gma * __builtin_amdgcn_sqrtf(d2));
          phb[rowL * P_PITCH + colh] = bf16t(ph);
        }
      }
    }
    // lgkm-only barrier: publishes phi, leaves wp/bp preloads in flight.
    soft_barrier();

    // ---- GEMM2: 8 k=32 steps (W fully preloaded) ----
#pragma unroll
    for (int ks = 0; ks < 8; ++ks) {
      short8 pv[2];
#pragma unroll
      for (int i = 0; i < 2; ++i)
        pv[i] = *(const short8*)(phb + (32 * wr + 16 * i + lm) * P_PITCH +
                                 ks * 32 + lg * 8);
#pragma unroll
      for (int i = 0; i < 2; ++i)
#pragma unroll
        for (int n = 0; n < 2; ++n)
          acc2[i][n] = __builtin_amdgcn_mfma_f32_16x16x32_bf16(
              pv[i], wp[ks][n], acc2[i][n], 0, 0, 0);
    }
  }

  // ---- out = acc2 + b, kout = 32wc + 16n + lm < 100 ----
#pragma unroll
  for (int i = 0; i < 2; ++i) {
#pragma unroll
    for (int n = 0; n < 2; ++n) {
      const int kout = 32 * wc + 16 * n + lm;
      if (kout < NK) {
        const float bb2 = bvec[kout];
#pragma unroll
        for (int r = 0; r < 4; ++r) {
          const int row = m0 + 32 * wr + 16 * i + 4 * lg + r;
          out[(size_t)row * NK + kout] = acc2[i][n][r] + bb2;
        }
      }
    }
  }
}

// ---------------- fallback (round-1 kernel, used if ws too small) ----------------

#define A_PITCH1 520
#define BW_PITCH1 72
#define PHI_PITCH1 264

__global__ __launch_bounds__(256, 1)
void rbf_fused_v1(const float* __restrict__ x, const float* __restrict__ ctr,
                  const float* __restrict__ gamma_p, const float* __restrict__ W,
                  const float* __restrict__ bvec, float* __restrict__ out) {
  __shared__ alignas(16) short a_lds[64 * A_PITCH1];
  __shared__ alignas(16) short bw_lds[256 * BW_PITCH1];
  __shared__ alignas(16) short phi_lds[64 * PHI_PITCH1];
  __shared__ float xsq[64];
  __shared__ float csq[256];

  const int tid = threadIdx.x;
  const int lane = tid & 63;
  const int wv = tid >> 6;
  const int lm = lane & 15;
  const int lg = lane >> 4;
  const int m0 = blockIdx.x * 64;
  const float gma = gamma_p[0];

  {
    const int row = tid >> 2;
    const int seg = tid & 3;
    const float* xr = x + (size_t)(m0 + row) * NF + seg * 128;
    short* ar = a_lds + row * A_PITCH1 + seg * 128;
    float xp = 0.f;
#pragma unroll
    for (int i = 0; i < 32; ++i) {
      f4 v = ((const f4*)xr)[i];
      xp += v.x * v.x + v.y * v.y + v.z * v.z + v.w * v.w;
      short4v h;
      h.x = bf16t(v.x); h.y = bf16t(v.y); h.z = bf16t(v.z); h.w = bf16t(v.w);
      *(short4v*)(ar + i * 4) = h;
    }
    ((float*)phi_lds)[tid] = xp;
  }
  __syncthreads();
  if (tid < 64) {
    const float* pp = (const float*)phi_lds;
    xsq[tid] = pp[tid * 4] + pp[tid * 4 + 1] + pp[tid * 4 + 2] + pp[tid * 4 + 3];
  }

  const f4 fzero = {0.f, 0.f, 0.f, 0.f};
  f4 acc2[4][2];
#pragma unroll
  for (int i = 0; i < 4; ++i)
#pragma unroll
    for (int n = 0; n < 2; ++n) acc2[i][n] = fzero;

  const short* a_base = a_lds + lm * A_PITCH1 + lg * 8;
  const short* b_base = bw_lds + (64 * wv + lm) * BW_PITCH1 + lg * 8;
  const short* w_base = bw_lds + lm * BW_PITCH1 + lg * 8;
  const short* p_base = phi_lds + lm * PHI_PITCH1 + lg * 8;

  for (int chunk = 0; chunk < 4; ++chunk) {
    const int c0 = chunk * 256;
    f4 acc1[4][4];
#pragma unroll
    for (int i = 0; i < 4; ++i)
#pragma unroll
      for (int t = 0; t < 4; ++t) acc1[i][t] = fzero;
    float cpriv = 0.f;

    for (int kb = 0; kb < 8; ++kb) {
      __syncthreads();
      {
        const float* cr = ctr + (size_t)(c0 + tid) * NF + kb * 64;
        short* br = bw_lds + tid * BW_PITCH1;
#pragma unroll
        for (int i = 0; i < 16; ++i) {
          f4 v = ((const f4*)cr)[i];
          cpriv += v.x * v.x + v.y * v.y + v.z * v.z + v.w * v.w;
          short4v h;
          h.x = bf16t(v.x); h.y = bf16t(v.y); h.z = bf16t(v.z); h.w = bf16t(v.w);
          *(short4v*)(br + i * 4) = h;
        }
      }
      __syncthreads();
#pragma unroll
      for (int s = 0; s < 2; ++s) {
        short8 av[4], bv8[4];
#pragma unroll
        for (int i = 0; i < 4; ++i)
          av[i] = *(const short8*)(a_base + 16 * i * A_PITCH1 + 64 * kb + 32 * s);
#pragma unroll
        for (int t = 0; t < 4; ++t)
          bv8[t] = *(const short8*)(b_base + 16 * t * BW_PITCH1 + 32 * s);
#pragma unroll
        for (int i = 0; i < 4; ++i)
#pragma unroll
          for (int t = 0; t < 4; ++t)
            acc1[i][t] = __builtin_amdgcn_mfma_f32_16x16x32_bf16(
                av[i], bv8[t], acc1[i][t], 0, 0, 0);
      }
    }

    csq[tid] = cpriv;
    __syncthreads();

#pragma unroll
    for (int i = 0; i < 4; ++i) {
#pragma unroll
      for (int t = 0; t < 4; ++t) {
        const int colL = 64 * wv + 16 * t + lm;
        const float cs = csq[colL];
#pragma unroll
        for (int r = 0; r < 4; ++r) {
          const int rowL = 16 * i + 4 * lg + r;
          float d2 = xsq[rowL] + cs - 2.0f * acc1[i][t][r];
          d2 = fmaxf(d2, 0.f);
          const float ph = __expf(-gma * __fsqrt_rn(d2));
          phi_lds[rowL * PHI_PITCH1 + colL] = bf16t(ph);
        }
      }
    }

    for (int u = 0; u < 4; ++u) {
      __syncthreads();
      {
        const int row = tid >> 1;
        const int half = tid & 1;
        short* wr = bw_lds + row * BW_PITCH1 + half * 32;
        if (row < NK) {
          const float* ws = W + (size_t)row * NC + c0 + u * 64 + half * 32;
#pragma unroll
          for (int i = 0; i < 8; ++i) {
            f4 v = ((const f4*)ws)[i];
            short4v h;
            h.x = bf16t(v.x); h.y = bf16t(v.y); h.z = bf16t(v.z); h.w = bf16t(v.w);
            *(short4v*)(wr + i * 4) = h;
          }
        } else {
          const short4v zz = {0, 0, 0, 0};
#pragma unroll
          for (int i = 0; i < 8; ++i) *(short4v*)(wr + i * 4) = zz;
        }
      }
      __syncthreads();
#pragma unroll
      for (int s = 0; s < 2; ++s) {
        short8 pv[4], wv8[2];
#pragma unroll
        for (int i = 0; i < 4; ++i)
          pv[i] = *(const short8*)(p_base + 16 * i * PHI_PITCH1 + 64 * u + 32 * s);
#pragma unroll
        for (int n = 0; n < 2; ++n)
          wv8[n] = *(const short8*)(w_base + 16 * (2 * wv + n) * BW_PITCH1 + 32 * s);
#pragma unroll
        for (int i = 0; i < 4; ++i)
#pragma unroll
          for (int n = 0; n < 2; ++n)
            acc2[i][n] = __builtin_amdgcn_mfma_f32_16x16x32_bf16(
                pv[i], wv8[n], acc2[i][n], 0, 0, 0);
      }
    }
  }

#pragma unroll
  for (int i = 0; i < 4; ++i) {
#pragma unroll
    for (int n = 0; n < 2; ++n) {
      const int kout = 32 * wv + 16 * n + lm;
      if (kout < NK) {
        const float bb = bvec[kout];
#pragma unroll
        for (int r = 0; r < 4; ++r) {
          const int row = m0 + 16 * i + 4 * lg + r;
          out[(size_t)row * NK + kout] = acc2[i][n][r] + bb;
        }
      }
    }
  }
}

extern "C" void kernel_launch(void* const* d_in, const int* in_sizes, int n_in,
                              void* d_out, int out_size, void* d_ws, size_t ws_size,
                              hipStream_t stream) {
  (void)in_sizes; (void)n_in; (void)out_size;
  const float* x       = (const float*)d_in[0];
  const float* centers = (const float*)d_in[1];
  const float* gamma   = (const float*)d_in[2];
  const float* W       = (const float*)d_in[3];
  const float* b       = (const float*)d_in[4];
  float* out = (float*)d_out;

  if (ws_size >= (size_t)WS_NEED) {
    char* wsb = (char*)d_ws;
    char*  cbp  = wsb;                                  // 512KB fp8 centers
    float* csqp = (float*)(wsb + CB_BYTES);             // 1024 f32
    char*  wbp  = wsb + CB_BYTES + NC * 4;              // 256KB bf16 W
    prep_all<<<dim3(34), dim3(256), 0, stream>>>(centers, W, cbp, csqp, wbp);
    rbf_main<<<dim3(NB / 64), dim3(512), 0, stream>>>(x, cbp, csqp, wbp, b,
                                                      gamma, out);
  } else {
    rbf_fused_v1<<<dim3(NB / 64), dim3(256), 0, stream>>>(x, centers, gamma, W,
                                                          b, out);
  }
}

// Round 3
// 110.505 us; speedup vs baseline: 1.0222x; 1.0222x over previous
//
#include <hip/hip_runtime.h>

// RBFNN fused, round 10: R8 geometry (M=32, 256 thr, 2 blk/CU) + lgkm-only
// barriers ONLY. Un-bundles R9's two changes after its regression.
// out[B,K] = exp(-gamma * dist(x, centers)) @ W^T + b
// B=16384, F=512, C=1024, K=100.
//
// R9 post-mortem: M=64 @ 512thr regressed (113.0 vs R8 110.9) because
// (a) wr0/wr1 wave pairs duplicate bp loads -> cb L2 traffic did NOT halve,
// (b) 102KB LDS -> 1 blk/CU lost cross-block latency hiding. The soft
// barrier itself passed refcheck. This round: R8 geometry byte-identical,
// with the three __syncthreads replaced by s_waitcnt lgkmcnt(0)+s_barrier.
// All barrier sites publish only LDS data (a_lds/partials/xsq/phi); the
// deliberate in-flight wp(16)+bp(8) global preloads no longer get
// force-drained 4x/block by vmcnt(0).

#define NB 16384
#define NF 512
#define NC 1024
#define NK 100

#define A_PITCH 528   // bytes/row (512 fp8 + 16 pad)
#define P_PITCH 264   // shorts/row (256 bf16 + 8 pad)

#define CB_BYTES (NC * NF)      // 512KB fp8 centers, MX-frag-ordered
#define WB_BYTES (256 * 1024)   // 256KB bf16 W (100->128 kouts), frag-ordered
#define WS_NEED (CB_BYTES + NC * 4 + WB_BYTES)

typedef __attribute__((ext_vector_type(8))) short short8;
typedef __attribute__((ext_vector_type(4))) short short4v;
typedef __attribute__((ext_vector_type(4))) float f4;
typedef __attribute__((ext_vector_type(4))) unsigned int uint4v;
typedef __attribute__((ext_vector_type(8))) int int8v;
typedef unsigned short ushort;
typedef unsigned int uint;

__device__ __forceinline__ short bf16t(float f) {
  return (short)(__float_as_uint(f) >> 16);
}

__device__ __forceinline__ uint pk4_fp8(float a, float b, float c, float d) {
  uint r = __builtin_amdgcn_cvt_pk_fp8_f32(a, b, 0, false);
  return __builtin_amdgcn_cvt_pk_fp8_f32(c, d, r, true);
}

// lgkm-only barrier: publishes LDS writes but leaves global preloads in
// flight (their consumers get compiler-counted vmcnt waits at first use).
__device__ __forceinline__ void soft_barrier() {
  asm volatile("s_waitcnt lgkmcnt(0)" ::: "memory");
  __builtin_amdgcn_s_barrier();
  asm volatile("" ::: "memory");
}

// ---------------- merged prepass (unchanged from R8) ----------------
// blocks 0..31: centers [1024,512] fp32 -> cb fp8 MX-fragment-ordered + csq.
//   cb addr ((c*4+ks)*16 + tg)*2048 + lane*32, lane = lg*16+lm:
//   32B = fp8 ctr[c*256 + tg*16 + lm][ks*128 + lg*32 .. +31]  (k-linear).
// blocks 32..33: W [100,1024] fp32 -> wb bf16 fragment-ordered, 128 kouts.
__global__ __launch_bounds__(256) void prep_all(
    const float* __restrict__ ctr, const float* __restrict__ W,
    char* __restrict__ cb, float* __restrict__ csq, char* __restrict__ wb) {
  if (blockIdx.x < 32) {
    const int t = blockIdx.x * 256 + threadIdx.x;  // 0..8191
    const int cg = t >> 3;                          // center row 0..1023
    const int kb = t & 7;                           // 64-k block
    const f4* src = (const f4*)(ctr + (size_t)cg * NF + kb * 64);
    float f[64];
    float ss = 0.f;
#pragma unroll
    for (int i = 0; i < 16; ++i) {
      f4 v = src[i];
      f[4 * i] = v.x; f[4 * i + 1] = v.y; f[4 * i + 2] = v.z; f[4 * i + 3] = v.w;
      ss += v.x * v.x + v.y * v.y + v.z * v.z + v.w * v.w;
    }
    uint w[16];
#pragma unroll
    for (int m = 0; m < 16; ++m)
      w[m] = pk4_fp8(f[4 * m], f[4 * m + 1], f[4 * m + 2], f[4 * m + 3]);
    const int c = cg >> 8, tg = (cg >> 4) & 15, lm = cg & 15;
    const int ks = kb >> 1, half = kb & 1;  // lg slots: half*2, half*2+1
    char* base = cb + (size_t)(((c * 4 + ks) * 16 + tg) << 11) + lm * 32 +
                 half * 1024;
    uint4v u0 = {w[0], w[1], w[2], w[3]};
    uint4v u1 = {w[4], w[5], w[6], w[7]};
    uint4v u2 = {w[8], w[9], w[10], w[11]};
    uint4v u3 = {w[12], w[13], w[14], w[15]};
    *(uint4v*)(base) = u0;          // lg slot half*2,   k-local  0..31
    *(uint4v*)(base + 16) = u1;
    *(uint4v*)(base + 512) = u2;    // lg slot half*2+1, k-local 32..63
    *(uint4v*)(base + 528) = u3;
    ss += __shfl_down(ss, 4, 64);
    ss += __shfl_down(ss, 2, 64);
    ss += __shfl_down(ss, 1, 64);
    if (kb == 0) csq[cg] = ss;
  } else {
    const int t = (blockIdx.x - 32) * 256 + threadIdx.x;  // 0..511
    const int kout = t >> 2, c = t & 3;
    const int kf = kout >> 4, lm = kout & 15;
#pragma unroll
    for (int ks = 0; ks < 8; ++ks) {
#pragma unroll
      for (int lg = 0; lg < 4; ++lg) {
        short4v h0 = {0, 0, 0, 0}, h1 = {0, 0, 0, 0};
        if (kout < NK) {
          const float* src = W + (size_t)kout * NC + c * 256 + ks * 32 + lg * 8;
          f4 v0 = ((const f4*)src)[0], v1 = ((const f4*)src)[1];
          h0.x = bf16t(v0.x); h0.y = bf16t(v0.y); h0.z = bf16t(v0.z); h0.w = bf16t(v0.w);
          h1.x = bf16t(v1.x); h1.y = bf16t(v1.y); h1.z = bf16t(v1.z); h1.w = bf16t(v1.w);
        }
        char* dst = wb + (size_t)((c * 8 + ks) * 8 + kf) * 1024 +
                    (lg * 16 + lm) * 16;
        *(short4v*)dst = h0;
        *(short4v*)(dst + 8) = h1;
      }
    }
  }
}

// ---------------- main kernel: M=32, 256 threads, 4 waves ----------------

__global__ __launch_bounds__(256, 2)
void rbf_main(const float* __restrict__ x, const char* __restrict__ cb2,
              const float* __restrict__ csqp, const char* __restrict__ wb2,
              const float* __restrict__ bvec, const float* __restrict__ gamma_p,
              float* __restrict__ out) {
  __shared__ alignas(16) char a_lds[32 * A_PITCH];        // 16896 B, x fp8
  __shared__ alignas(16) short phi_lds[2][32 * P_PITCH];  // 33792 B, phi dbuf
  __shared__ float xsq[32];

  const int tid = threadIdx.x;
  const int lane = tid & 63;
  const int wv = tid >> 6;   // 0..3
  const int lm = lane & 15;
  const int lg = lane >> 4;
  const int m0 = blockIdx.x * 32;
  const float gma = gamma_p[0];
  const int laneoff32 = lane << 5;  // 32B B-frags (MX K=128)
  const int laneoff16 = lane << 4;  // 16B W-frags

  // ---- prologue: stage x tile (fp32->fp8, k-LINEAR) + xsq ----
  {
    const int row = tid >> 3;   // 0..31
    const int seg = tid & 7;    // k block of 64
    const f4* xr = (const f4*)(x + (size_t)(m0 + row) * NF + seg * 64);
    float f[64];
    float ss = 0.f;
#pragma unroll
    for (int i = 0; i < 16; ++i) {
      f4 v = xr[i];
      f[4 * i] = v.x; f[4 * i + 1] = v.y; f[4 * i + 2] = v.z; f[4 * i + 3] = v.w;
      ss += v.x * v.x + v.y * v.y + v.z * v.z + v.w * v.w;
    }
    uint w[16];
#pragma unroll
    for (int m = 0; m < 16; ++m)
      w[m] = pk4_fp8(f[4 * m], f[4 * m + 1], f[4 * m + 2], f[4 * m + 3]);
    char* ar = a_lds + row * A_PITCH + seg * 64;
#pragma unroll
    for (int l2 = 0; l2 < 4; ++l2) {
      uint4v u = {w[4 * l2], w[4 * l2 + 1], w[4 * l2 + 2], w[4 * l2 + 3]};
      *(uint4v*)(ar + l2 * 16) = u;  // byte offset == k (linear)
    }
    ((float*)phi_lds[0])[tid] = ss;  // scratch partials (consumed pre-E0)
  }

  // B frag ring buffer (32B/frag); preload chunk-0 stages ks=0,1
  int8v bp[3][4];
#pragma unroll
  for (int t = 0; t < 4; ++t) {
    bp[0][t] = *(const int8v*)(cb2 + ((wv + 4 * t) << 11) + laneoff32);
    bp[1][t] = *(const int8v*)(cb2 + ((16 + wv + 4 * t) << 11) + laneoff32);
  }

  soft_barrier();  // publishes a_lds + partials (bp loads stay in flight)
  if (tid < 32) {
    const float* pp = (const float*)phi_lds[0] + 8 * tid;
    xsq[tid] = pp[0] + pp[1] + pp[2] + pp[3] + pp[4] + pp[5] + pp[6] + pp[7];
  }
  soft_barrier();  // publishes xsq

  const f4 fzero = {0.f, 0.f, 0.f, 0.f};
  f4 acc2[2][2];
#pragma unroll
  for (int i = 0; i < 2; ++i)
#pragma unroll
    for (int n = 0; n < 2; ++n) acc2[i][n] = fzero;

  for (int c = 0; c < 4; ++c) {
    float csr[4];
#pragma unroll
    for (int t = 0; t < 4; ++t)
      csr[t] = csqp[c * 256 + 16 * (wv + 4 * t) + lm];

    f4 acc1[2][4];
#pragma unroll
    for (int i = 0; i < 2; ++i)
#pragma unroll
      for (int t = 0; t < 4; ++t) acc1[i][t] = fzero;

    // ---- GEMM1: 4 k=128 MX stages, no barriers, B ring-3 (distance 2) ----
    const char* bb = cb2 + (size_t)c * 131072;
#pragma unroll
    for (int ks = 0; ks < 4; ++ks) {
      if (ks < 2) {
#pragma unroll
        for (int t = 0; t < 4; ++t)
          bp[(ks + 2) % 3][t] = *(const int8v*)(
              bb + ((((ks + 2) * 16) + wv + 4 * t) << 11) + laneoff32);
      }
      int8v a2[2];
#pragma unroll
      for (int i = 0; i < 2; ++i)
        a2[i] = *(const int8v*)(a_lds + (16 * i + lm) * A_PITCH + ks * 128 +
                                lg * 32);
      const int cur = ks % 3;
#pragma unroll
      for (int i = 0; i < 2; ++i)
#pragma unroll
        for (int t = 0; t < 4; ++t)
          acc1[i][t] = __builtin_amdgcn_mfma_scale_f32_16x16x128_f8f6f4(
              a2[i], bp[cur][t], acc1[i][t],
              0 /*fmt A=e4m3*/, 0 /*fmt B=e4m3*/,
              0, 0x7F7F7F7F,    /* scale A = 1.0 */
              0, 0x7F7F7F7F);   /* scale B = 1.0 */
    }

    // ---- preloads (in flight across epilogue + soft barrier) ----
    const char* wwb = wb2 + (size_t)c * 65536;
    short8 wp[8][2];
#pragma unroll
    for (int ks = 0; ks < 8; ++ks)
#pragma unroll
      for (int n = 0; n < 2; ++n)
        wp[ks][n] = *(const short8*)(wwb + ((ks * 8 + 2 * wv + n) << 10) +
                                     laneoff16);
    if (c < 3) {
      const char* bbn = cb2 + (size_t)(c + 1) * 131072;
#pragma unroll
      for (int t = 0; t < 4; ++t) {
        bp[0][t] = *(const int8v*)(bbn + ((wv + 4 * t) << 11) + laneoff32);
        bp[1][t] = *(const int8v*)(bbn + ((16 + wv + 4 * t) << 11) + laneoff32);
      }
    }

    // ---- epilogue: phi = exp(-gamma*dist) -> phi_lds[c&1] (A layout) ----
    short* phb = phi_lds[c & 1];
#pragma unroll
    for (int t = 0; t < 4; ++t) {
      const float cs = csr[t];
      const int colh = 16 * (wv + 4 * t) + lm;
#pragma unroll
      for (int i = 0; i < 2; ++i) {
#pragma unroll
        for (int r = 0; r < 4; ++r) {
          const int rowL = 16 * i + 4 * lg + r;
          float d2 = xsq[rowL] + cs - 2.0f * acc1[i][t][r];
          d2 = fmaxf(d2, 0.f);
          const float ph = __expf(-gma * __builtin_amdgcn_sqrtf(d2));
          phb[rowL * P_PITCH + colh] = bf16t(ph);
        }
      }
    }
    // the chunk's ONLY barrier: publishes phi, leaves wp/bp in flight
    soft_barrier();

    // ---- GEMM2: 8 k=32 steps, zero global stalls (W fully preloaded) ----
#pragma unroll
    for (int ks = 0; ks < 8; ++ks) {
      short8 pv[2];
#pragma unroll
      for (int i = 0; i < 2; ++i)
        pv[i] = *(const short8*)(phb + (16 * i + lm) * P_PITCH + ks * 32 +
                                 lg * 8);
#pragma unroll
      for (int i = 0; i < 2; ++i)
#pragma unroll
        for (int n = 0; n < 2; ++n)
          acc2[i][n] = __builtin_amdgcn_mfma_f32_16x16x32_bf16(
              pv[i], wp[ks][n], acc2[i][n], 0, 0, 0);
    }
  }

  // ---- out = acc2 + b, kout = 32wv + 16n + lm < 100 ----
#pragma unroll
  for (int i = 0; i < 2; ++i) {
#pragma unroll
    for (int n = 0; n < 2; ++n) {
      const int kout = 32 * wv + 16 * n + lm;
      if (kout < NK) {
        const float bb2 = bvec[kout];
#pragma unroll
        for (int r = 0; r < 4; ++r) {
          const int row = m0 + 16 * i + 4 * lg + r;
          out[(size_t)row * NK + kout] = acc2[i][n][r] + bb2;
        }
      }
    }
  }
}

// ---------------- fallback (round-1 kernel, used if ws too small) ----------------

#define A_PITCH1 520
#define BW_PITCH1 72
#define PHI_PITCH1 264

__global__ __launch_bounds__(256, 1)
void rbf_fused_v1(const float* __restrict__ x, const float* __restrict__ ctr,
                  const float* __restrict__ gamma_p, const float* __restrict__ W,
                  const float* __restrict__ bvec, float* __restrict__ out) {
  __shared__ alignas(16) short a_lds[64 * A_PITCH1];
  __shared__ alignas(16) short bw_lds[256 * BW_PITCH1];
  __shared__ alignas(16) short phi_lds[64 * PHI_PITCH1];
  __shared__ float xsq[64];
  __shared__ float csq[256];

  const int tid = threadIdx.x;
  const int lane = tid & 63;
  const int wv = tid >> 6;
  const int lm = lane & 15;
  const int lg = lane >> 4;
  const int m0 = blockIdx.x * 64;
  const float gma = gamma_p[0];

  {
    const int row = tid >> 2;
    const int seg = tid & 3;
    const float* xr = x + (size_t)(m0 + row) * NF + seg * 128;
    short* ar = a_lds + row * A_PITCH1 + seg * 128;
    float xp = 0.f;
#pragma unroll
    for (int i = 0; i < 32; ++i) {
      f4 v = ((const f4*)xr)[i];
      xp += v.x * v.x + v.y * v.y + v.z * v.z + v.w * v.w;
      short4v h;
      h.x = bf16t(v.x); h.y = bf16t(v.y); h.z = bf16t(v.z); h.w = bf16t(v.w);
      *(short4v*)(ar + i * 4) = h;
    }
    ((float*)phi_lds)[tid] = xp;
  }
  __syncthreads();
  if (tid < 64) {
    const float* pp = (const float*)phi_lds;
    xsq[tid] = pp[tid * 4] + pp[tid * 4 + 1] + pp[tid * 4 + 2] + pp[tid * 4 + 3];
  }

  const f4 fzero = {0.f, 0.f, 0.f, 0.f};
  f4 acc2[4][2];
#pragma unroll
  for (int i = 0; i < 4; ++i)
#pragma unroll
    for (int n = 0; n < 2; ++n) acc2[i][n] = fzero;

  const short* a_base = a_lds + lm * A_PITCH1 + lg * 8;
  const short* b_base = bw_lds + (64 * wv + lm) * BW_PITCH1 + lg * 8;
  const short* w_base = bw_lds + lm * BW_PITCH1 + lg * 8;
  const short* p_base = phi_lds + lm * PHI_PITCH1 + lg * 8;

  for (int chunk = 0; chunk < 4; ++chunk) {
    const int c0 = chunk * 256;
    f4 acc1[4][4];
#pragma unroll
    for (int i = 0; i < 4; ++i)
#pragma unroll
      for (int t = 0; t < 4; ++t) acc1[i][t] = fzero;
    float cpriv = 0.f;

    for (int kb = 0; kb < 8; ++kb) {
      __syncthreads();
      {
        const float* cr = ctr + (size_t)(c0 + tid) * NF + kb * 64;
        short* br = bw_lds + tid * BW_PITCH1;
#pragma unroll
        for (int i = 0; i < 16; ++i) {
          f4 v = ((const f4*)cr)[i];
          cpriv += v.x * v.x + v.y * v.y + v.z * v.z + v.w * v.w;
          short4v h;
          h.x = bf16t(v.x); h.y = bf16t(v.y); h.z = bf16t(v.z); h.w = bf16t(v.w);
          *(short4v*)(br + i * 4) = h;
        }
      }
      __syncthreads();
#pragma unroll
      for (int s = 0; s < 2; ++s) {
        short8 av[4], bv8[4];
#pragma unroll
        for (int i = 0; i < 4; ++i)
          av[i] = *(const short8*)(a_base + 16 * i * A_PITCH1 + 64 * kb + 32 * s);
#pragma unroll
        for (int t = 0; t < 4; ++t)
          bv8[t] = *(const short8*)(b_base + 16 * t * BW_PITCH1 + 32 * s);
#pragma unroll
        for (int i = 0; i < 4; ++i)
#pragma unroll
          for (int t = 0; t < 4; ++t)
            acc1[i][t] = __builtin_amdgcn_mfma_f32_16x16x32_bf16(
                av[i], bv8[t], acc1[i][t], 0, 0, 0);
      }
    }

    csq[tid] = cpriv;
    __syncthreads();

#pragma unroll
    for (int i = 0; i < 4; ++i) {
#pragma unroll
      for (int t = 0; t < 4; ++t) {
        const int colL = 64 * wv + 16 * t + lm;
        const float cs = csq[colL];
#pragma unroll
        for (int r = 0; r < 4; ++r) {
          const int rowL = 16 * i + 4 * lg + r;
          float d2 = xsq[rowL] + cs - 2.0f * acc1[i][t][r];
          d2 = fmaxf(d2, 0.f);
          const float ph = __expf(-gma * __fsqrt_rn(d2));
          phi_lds[rowL * PHI_PITCH1 + colL] = bf16t(ph);
        }
      }
    }

    for (int u = 0; u < 4; ++u) {
      __syncthreads();
      {
        const int row = tid >> 1;
        const int half = tid & 1;
        short* wr = bw_lds + row * BW_PITCH1 + half * 32;
        if (row < NK) {
          const float* ws = W + (size_t)row * NC + c0 + u * 64 + half * 32;
#pragma unroll
          for (int i = 0; i < 8; ++i) {
            f4 v = ((const f4*)ws)[i];
            short4v h;
            h.x = bf16t(v.x); h.y = bf16t(v.y); h.z = bf16t(v.z); h.w = bf16t(v.w);
            *(short4v*)(wr + i * 4) = h;
          }
        } else {
          const short4v zz = {0, 0, 0, 0};
#pragma unroll
          for (int i = 0; i < 8; ++i) *(short4v*)(wr + i * 4) = zz;
        }
      }
      __syncthreads();
#pragma unroll
      for (int s = 0; s < 2; ++s) {
        short8 pv[4], wv8[2];
#pragma unroll
        for (int i = 0; i < 4; ++i)
          pv[i] = *(const short8*)(p_base + 16 * i * PHI_PITCH1 + 64 * u + 32 * s);
#pragma unroll
        for (int n = 0; n < 2; ++n)
          wv8[n] = *(const short8*)(w_base + 16 * (2 * wv + n) * BW_PITCH1 + 32 * s);
#pragma unroll
        for (int i = 0; i < 4; ++i)
#pragma unroll
          for (int n = 0; n < 2; ++n)
            acc2[i][n] = __builtin_amdgcn_mfma_f32_16x16x32_bf16(
                pv[i], wv8[n], acc2[i][n], 0, 0, 0);
      }
    }
  }

#pragma unroll
  for (int i = 0; i < 4; ++i) {
#pragma unroll
    for (int n = 0; n < 2; ++n) {
      const int kout = 32 * wv + 16 * n + lm;
      if (kout < NK) {
        const float bb = bvec[kout];
#pragma unroll
        for (int r = 0; r < 4; ++r) {
          const int row = m0 + 16 * i + 4 * lg + r;
          out[(size_t)row * NK + kout] = acc2[i][n][r] + bb;
        }
      }
    }
  }
}

extern "C" void kernel_launch(void* const* d_in, const int* in_sizes, int n_in,
                              void* d_out, int out_size, void* d_ws, size_t ws_size,
                              hipStream_t stream) {
  (void)in_sizes; (void)n_in; (void)out_size;
  const float* x       = (const float*)d_in[0];
  const float* centers = (const float*)d_in[1];
  const float* gamma   = (const float*)d_in[2];
  const float* W       = (const float*)d_in[3];
  const float* b       = (const float*)d_in[4];
  float* out = (float*)d_out;

  if (ws_size >= (size_t)WS_NEED) {
    char* wsb = (char*)d_ws;
    char*  cbp  = wsb;                                  // 512KB fp8 centers
    float* csqp = (float*)(wsb + CB_BYTES);             // 1024 f32
    char*  wbp  = wsb + CB_BYTES + NC * 4;              // 256KB bf16 W
    prep_all<<<dim3(34), dim3(256), 0, stream>>>(centers, W, cbp, csqp, wbp);
    rbf_main<<<dim3(NB / 32), dim3(256), 0, stream>>>(x, cbp, csqp, wbp, b,
                                                      gamma, out);
  } else {
    rbf_fused_v1<<<dim3(NB / 64), dim3(256), 0, stream>>>(x, centers, gamma, W,
                                                          b, out);
  }
}